// Round 1
// baseline (1103.797 us; speedup 1.0000x reference)
//
#include <hip/hip_runtime.h>
#include <hip/hip_bf16.h>

#define DIM   384
#define NH    12
#define HD    32
#define BATCH 32
#define HH    56
#define WW_   56
#define LTOK  3136
#define MTOK  100352
#define KDIM  384

typedef __attribute__((ext_vector_type(8))) short          bf16x8;
typedef __attribute__((ext_vector_type(4))) float          f32x4;
typedef __attribute__((ext_vector_type(4))) unsigned short u16x4;

static __device__ __forceinline__ unsigned short f2bf(float f) {
    __hip_bfloat16 h = __float2bfloat16(f);
    unsigned short u; __builtin_memcpy(&u, &h, 2); return u;
}
static __device__ __forceinline__ float bf2f(unsigned short s) {
    unsigned int u = ((unsigned int)s) << 16;
    float f; __builtin_memcpy(&f, &u, 4); return f;
}

// ---- fp32 -> bf16 bulk convert (x) ----
__global__ __launch_bounds__(256) void cvt_x_kernel(const float* __restrict__ in,
                                                    unsigned short* __restrict__ out, int n4) {
    int i = blockIdx.x * 256 + threadIdx.x;
    if (i >= n4) return;
    f32x4 v = *(const f32x4*)(in + 4 * (size_t)i);
    u16x4 u;
    u[0] = f2bf(v[0]); u[1] = f2bf(v[1]); u[2] = f2bf(v[2]); u[3] = f2bf(v[3]);
    *(u16x4*)(out + 4 * (size_t)i) = u;
}

// ---- fp32 -> bf16 weights convert ----
__global__ __launch_bounds__(256) void cvt_w_kernel(const float* __restrict__ qw,
                                                    const float* __restrict__ pw,
                                                    unsigned short* __restrict__ qwb,
                                                    unsigned short* __restrict__ pwb) {
    int i = blockIdx.x * 256 + threadIdx.x;
    if (i < 3 * DIM * DIM) {
        qwb[i] = f2bf(qw[i]);
    } else {
        int j = i - 3 * DIM * DIM;
        if (j < DIM * DIM) pwb[j] = f2bf(pw[j]);
    }
}

// ---- C[M,N] = A[M,384] @ W[N,384]^T + bias ; per-block: 128 rows x full N ----
// mfma_f32_16x16x32_bf16 layouts (guide-verified):
//   A-frag: m = lane&15, k = (lane>>4)*8 + j   (8 contiguous bf16 along K)
//   B-frag: n = lane&15, k = (lane>>4)*8 + j   (rows of W, contiguous along K)
//   C/D   : col = lane&15, row = (lane>>4)*4 + reg
template<bool OUT_BF16>
__global__ __launch_bounds__(256) void gemm_bt(const unsigned short* __restrict__ A,
                                               const unsigned short* __restrict__ W,
                                               const float* __restrict__ bias,
                                               void* __restrict__ Cout,
                                               int N, int nbn) {
    const int lane  = threadIdx.x & 63;
    const int wave  = threadIdx.x >> 6;
    const int wm    = wave >> 1, wn = wave & 1;
    const int row16 = lane & 15, quad = lane >> 4;
    const int koff  = quad * 8;
    const int m_base = blockIdx.x * 128 + wm * 64;

    const unsigned short* Ap[4];
    #pragma unroll
    for (int i = 0; i < 4; i++)
        Ap[i] = A + (size_t)(m_base + i * 16 + row16) * KDIM + koff;

    for (int bn = 0; bn < nbn; bn++) {
        const int n_base = bn * 128 + wn * 64;
        const unsigned short* Wp[4];
        #pragma unroll
        for (int j = 0; j < 4; j++)
            Wp[j] = W + (size_t)(n_base + j * 16 + row16) * KDIM + koff;

        f32x4 acc[4][4] = {};
        for (int k0 = 0; k0 < KDIM; k0 += 32) {
            bf16x8 a[4], b[4];
            #pragma unroll
            for (int i = 0; i < 4; i++) a[i] = *(const bf16x8*)(Ap[i] + k0);
            #pragma unroll
            for (int j = 0; j < 4; j++) b[j] = *(const bf16x8*)(Wp[j] + k0);
            #pragma unroll
            for (int i = 0; i < 4; i++) {
                #pragma unroll
                for (int j = 0; j < 4; j++)
                    acc[i][j] = __builtin_amdgcn_mfma_f32_16x16x32_bf16(a[i], b[j], acc[i][j], 0, 0, 0);
            }
        }

        #pragma unroll
        for (int j = 0; j < 4; j++) {
            const int col = n_base + j * 16 + row16;
            const float bv = bias[col];
            #pragma unroll
            for (int i = 0; i < 4; i++) {
                const int row0 = m_base + i * 16 + quad * 4;
                #pragma unroll
                for (int r = 0; r < 4; r++) {
                    float v = acc[i][j][r] + bv;
                    size_t off = (size_t)(row0 + r) * N + col;
                    if (OUT_BF16) ((unsigned short*)Cout)[off] = f2bf(v);
                    else          ((float*)Cout)[off]          = v;
                }
            }
        }
    }
}

// ---- per-(window,head) attention: 64 threads, thread t = query row t (t<49) ----
__global__ __launch_bounds__(64) void attn_win(const unsigned short* __restrict__ qkv,
                                               unsigned short* __restrict__ out) {
    __shared__ float ks[49][36];   // pad 36: 16B-aligned rows, near-conflict-free stores
    __shared__ float vs[49][36];
    const int t  = threadIdx.x;
    const int h  = blockIdx.x % NH;
    const int w  = blockIdx.x / NH;
    const int b  = w >> 6;
    const int wi = w & 63;
    const int wy = wi >> 3, wx = wi & 7;

    int tok = 0;
    if (t < 49) {
        tok = b * LTOK + (wy * 7 + t / 7) * WW_ + wx * 7 + (t % 7);
        const u16x4* kp = (const u16x4*)(qkv + (size_t)tok * 1152 + 384 + h * 32);
        const u16x4* vp = (const u16x4*)(qkv + (size_t)tok * 1152 + 768 + h * 32);
        #pragma unroll
        for (int c = 0; c < 8; c++) {
            u16x4 ku = kp[c], vu = vp[c];
            #pragma unroll
            for (int e = 0; e < 4; e++) {
                ks[t][4 * c + e] = bf2f(ku[e]);
                vs[t][4 * c + e] = bf2f(vu[e]);
            }
        }
    }
    __syncthreads();
    if (t >= 49) return;

    const float scale = 0.17677669529663687f;  // 32^-0.5
    float q[HD];
    {
        const u16x4* qp = (const u16x4*)(qkv + (size_t)tok * 1152 + h * 32);
        #pragma unroll
        for (int c = 0; c < 8; c++) {
            u16x4 u = qp[c];
            #pragma unroll
            for (int e = 0; e < 4; e++) q[4 * c + e] = bf2f(u[e]) * scale;
        }
    }

    float s[49];
    float mx = -1e30f;
    #pragma unroll
    for (int j = 0; j < 49; j++) {
        const f32x4* kr = (const f32x4*)ks[j];
        float acc = 0.f;
        #pragma unroll
        for (int c = 0; c < 8; c++) {
            f32x4 kv = kr[c];
            acc += q[4 * c + 0] * kv[0] + q[4 * c + 1] * kv[1]
                 + q[4 * c + 2] * kv[2] + q[4 * c + 3] * kv[3];
        }
        s[j] = acc;
        mx = fmaxf(mx, acc);
    }
    float l = 0.f;
    #pragma unroll
    for (int j = 0; j < 49; j++) { float e = __expf(s[j] - mx); s[j] = e; l += e; }
    const float inv = 1.0f / l;

    float o[HD] = {};
    #pragma unroll
    for (int j = 0; j < 49; j++) {
        const float p = s[j];
        const f32x4* vr = (const f32x4*)vs[j];
        #pragma unroll
        for (int c = 0; c < 8; c++) {
            f32x4 vv = vr[c];
            o[4 * c + 0] += p * vv[0]; o[4 * c + 1] += p * vv[1];
            o[4 * c + 2] += p * vv[2]; o[4 * c + 3] += p * vv[3];
        }
    }

    unsigned short* op = out + (size_t)tok * DIM + h * 32;
    #pragma unroll
    for (int c = 0; c < 8; c++) {
        u16x4 u;
        u[0] = f2bf(o[4 * c + 0] * inv); u[1] = f2bf(o[4 * c + 1] * inv);
        u[2] = f2bf(o[4 * c + 2] * inv); u[3] = f2bf(o[4 * c + 3] * inv);
        *(u16x4*)(op + 4 * c) = u;
    }
}

extern "C" void kernel_launch(void* const* d_in, const int* in_sizes, int n_in,
                              void* d_out, int out_size, void* d_ws, size_t ws_size,
                              hipStream_t stream) {
    const float* x      = (const float*)d_in[0];
    const float* qkv_w  = (const float*)d_in[1];
    const float* qkv_b  = (const float*)d_in[2];
    const float* proj_w = (const float*)d_in[3];
    const float* proj_b = (const float*)d_in[4];
    float* out = (float*)d_out;

    char* ws = (char*)d_ws;
    // layout: [qkv bf16: MTOK*1152] [x_bf / attn_out (aliased): MTOK*384] [qkv_w bf16] [proj_w bf16]
    unsigned short* qkv_bf = (unsigned short*)ws;
    unsigned short* xa_bf  = (unsigned short*)(ws + (size_t)MTOK * 1152 * 2);
    unsigned short* qw_bf  = (unsigned short*)(ws + (size_t)MTOK * 1152 * 2 + (size_t)MTOK * DIM * 2);
    unsigned short* pw_bf  = qw_bf + 3 * DIM * DIM;

    const int n4 = MTOK * DIM / 4;
    cvt_x_kernel<<<(n4 + 255) / 256, 256, 0, stream>>>(x, xa_bf, n4);
    cvt_w_kernel<<<(4 * DIM * DIM + 255) / 256, 256, 0, stream>>>(qkv_w, proj_w, qw_bf, pw_bf);

    // QKV: A = x_bf, W = qkv_w bf16, out = qkv_bf (N = 1152, nbn = 9)
    gemm_bt<true><<<MTOK / 128, 256, 0, stream>>>(xa_bf, qw_bf, qkv_b, qkv_bf, 3 * DIM, 9);

    // attention: reads qkv_bf, writes attn_out into xa_bf (x_bf is dead after QKV GEMM)
    attn_win<<<2048 * NH, 64, 0, stream>>>(qkv_bf, xa_bf);

    // proj: A = attn_out bf16, out = d_out fp32 (N = 384, nbn = 3)
    gemm_bt<false><<<MTOK / 128, 256, 0, stream>>>(xa_bf, pw_bf, proj_b, out, DIM, 3);
}

// Round 2
// 788.860 us; speedup vs baseline: 1.3992x; 1.3992x over previous
//
#include <hip/hip_runtime.h>
#include <hip/hip_bf16.h>

#define DIM   384
#define NH    12
#define HD    32
#define BATCH 32
#define HH    56
#define WW_   56
#define LTOK  3136
#define MTOK  100352
#define KDIM  384
#define BK    64

typedef __attribute__((ext_vector_type(8))) short          bf16x8;
typedef __attribute__((ext_vector_type(4))) float          f32x4;
typedef __attribute__((ext_vector_type(4))) unsigned short u16x4;

static __device__ __forceinline__ unsigned short f2bf(float f) {
    __hip_bfloat16 h = __float2bfloat16(f);
    unsigned short u; __builtin_memcpy(&u, &h, 2); return u;
}
static __device__ __forceinline__ float bf2f(unsigned short s) {
    unsigned int u = ((unsigned int)s) << 16;
    float f; __builtin_memcpy(&f, &u, 4); return f;
}

static __device__ __forceinline__ void async_cp16(const unsigned short* g, unsigned short* l) {
    __builtin_amdgcn_global_load_lds((const __attribute__((address_space(1))) void*)g,
                                     (__attribute__((address_space(3))) void*)l, 16, 0, 0);
}

// ---- fp32 -> bf16 bulk convert (x) ----
__global__ __launch_bounds__(256) void cvt_x_kernel(const float* __restrict__ in,
                                                    unsigned short* __restrict__ out, int n4) {
    int i = blockIdx.x * 256 + threadIdx.x;
    if (i >= n4) return;
    f32x4 v = *(const f32x4*)(in + 4 * (size_t)i);
    u16x4 u;
    u[0] = f2bf(v[0]); u[1] = f2bf(v[1]); u[2] = f2bf(v[2]); u[3] = f2bf(v[3]);
    *(u16x4*)(out + 4 * (size_t)i) = u;
}

__global__ __launch_bounds__(256) void cvt_w_kernel(const float* __restrict__ qw,
                                                    const float* __restrict__ pw,
                                                    unsigned short* __restrict__ qwb,
                                                    unsigned short* __restrict__ pwb) {
    int i = blockIdx.x * 256 + threadIdx.x;
    if (i < 3 * DIM * DIM) {
        qwb[i] = f2bf(qw[i]);
    } else {
        int j = i - 3 * DIM * DIM;
        if (j < DIM * DIM) pwb[j] = f2bf(pw[j]);
    }
}

// ---- LDS-staged GEMM: C[M,N] = A[M,384] @ W[N,384]^T + bias ----
// Block = 128x128 C-tile, 4 waves in 2x2, each wave 64x64 (4x4 mfma tiles).
// Staging: global_load_lds width=16; LDS tile [128][BK] bf16, 16B chunk index
// XOR-swizzled by (row&7) so ds_read_b128 fragment reads are 2-way (free).
// grid: blockIdx.x = mt * nbn + nt  (n fastest -> same-m blocks concurrent,
// A rows fetched from HBM once, re-reads hit L2/L3)
template<bool OUT_BF16>
__global__ __launch_bounds__(256) void gemm_bt(const unsigned short* __restrict__ A,
                                               const unsigned short* __restrict__ W,
                                               const float* __restrict__ bias,
                                               void* __restrict__ Cout,
                                               int N, int nbn) {
    __shared__ unsigned short ldsA[128 * BK];
    __shared__ unsigned short ldsB[128 * BK];

    const int tid   = threadIdx.x;
    const int lane  = tid & 63;
    const int wave  = tid >> 6;
    const int wm    = wave >> 1, wn = wave & 1;
    const int row16 = lane & 15, quad = lane >> 4;

    const int mt = blockIdx.x / nbn;
    const int nt = blockIdx.x % nbn;
    const int m_base = mt * 128;
    const int n_base = nt * 128;

    const unsigned short* Abase = A + (size_t)m_base * KDIM;
    const unsigned short* Wbase = W + (size_t)n_base * KDIM;

    // staging coordinates for this thread (4 chunks each for A and B)
    int srow[4], skc[4];
    #pragma unroll
    for (int i = 0; i < 4; i++) {
        int c = i * 256 + tid;          // chunk index 0..1023
        srow[i] = c >> 3;               // row 0..127
        int cpos = c & 7;               // chunk position within row
        skc[i] = cpos ^ (srow[i] & 7);  // which global chunk lives here
    }

    f32x4 acc[4][4] = {};

    for (int kb = 0; kb < KDIM / BK; kb++) {
        const int k0 = kb * BK;
        #pragma unroll
        for (int i = 0; i < 4; i++) {
            const unsigned short* ga = Abase + (size_t)srow[i] * KDIM + k0 + skc[i] * 8;
            async_cp16(ga, ldsA + (i * 256 + wave * 64) * 8);
        }
        #pragma unroll
        for (int i = 0; i < 4; i++) {
            const unsigned short* gb = Wbase + (size_t)srow[i] * KDIM + k0 + skc[i] * 8;
            async_cp16(gb, ldsB + (i * 256 + wave * 64) * 8);
        }
        __syncthreads();

        #pragma unroll
        for (int ks = 0; ks < 2; ks++) {
            const int kc = ks * 4 + quad;
            bf16x8 a[4], b[4];
            #pragma unroll
            for (int i = 0; i < 4; i++) {
                const int row = wm * 64 + i * 16 + row16;
                a[i] = *(const bf16x8*)(ldsA + row * BK + (kc ^ (row & 7)) * 8);
            }
            #pragma unroll
            for (int j = 0; j < 4; j++) {
                const int row = wn * 64 + j * 16 + row16;
                b[j] = *(const bf16x8*)(ldsB + row * BK + (kc ^ (row & 7)) * 8);
            }
            #pragma unroll
            for (int i = 0; i < 4; i++) {
                #pragma unroll
                for (int j = 0; j < 4; j++)
                    acc[i][j] = __builtin_amdgcn_mfma_f32_16x16x32_bf16(a[i], b[j], acc[i][j], 0, 0, 0);
            }
        }
        __syncthreads();
    }

    #pragma unroll
    for (int j = 0; j < 4; j++) {
        const int col = n_base + wn * 64 + j * 16 + row16;
        const float bv = bias[col];
        #pragma unroll
        for (int i = 0; i < 4; i++) {
            const int row0 = m_base + wm * 64 + i * 16 + quad * 4;
            #pragma unroll
            for (int r = 0; r < 4; r++) {
                float v = acc[i][j][r] + bv;
                size_t off = (size_t)(row0 + r) * N + col;
                if (OUT_BF16) ((unsigned short*)Cout)[off] = f2bf(v);
                else          ((float*)Cout)[off]          = v;
            }
        }
    }
}

// ---- per-(window,head) attention: 64 threads, thread t = query row t (t<49) ----
__global__ __launch_bounds__(64) void attn_win(const unsigned short* __restrict__ qkv,
                                               unsigned short* __restrict__ out) {
    __shared__ float ks[49][36];
    __shared__ float vs[49][36];
    const int t  = threadIdx.x;
    const int h  = blockIdx.x % NH;
    const int w  = blockIdx.x / NH;
    const int b  = w >> 6;
    const int wi = w & 63;
    const int wy = wi >> 3, wx = wi & 7;

    int tok = 0;
    if (t < 49) {
        tok = b * LTOK + (wy * 7 + t / 7) * WW_ + wx * 7 + (t % 7);
        const u16x4* kp = (const u16x4*)(qkv + (size_t)tok * 1152 + 384 + h * 32);
        const u16x4* vp = (const u16x4*)(qkv + (size_t)tok * 1152 + 768 + h * 32);
        #pragma unroll
        for (int c = 0; c < 8; c++) {
            u16x4 ku = kp[c], vu = vp[c];
            #pragma unroll
            for (int e = 0; e < 4; e++) {
                ks[t][4 * c + e] = bf2f(ku[e]);
                vs[t][4 * c + e] = bf2f(vu[e]);
            }
        }
    }
    __syncthreads();
    if (t >= 49) return;

    const float scale = 0.17677669529663687f;  // 32^-0.5
    float q[HD];
    {
        const u16x4* qp = (const u16x4*)(qkv + (size_t)tok * 1152 + h * 32);
        #pragma unroll
        for (int c = 0; c < 8; c++) {
            u16x4 u = qp[c];
            #pragma unroll
            for (int e = 0; e < 4; e++) q[4 * c + e] = bf2f(u[e]) * scale;
        }
    }

    float s[49];
    float mx = -1e30f;
    #pragma unroll
    for (int j = 0; j < 49; j++) {
        const f32x4* kr = (const f32x4*)ks[j];
        float acc = 0.f;
        #pragma unroll
        for (int c = 0; c < 8; c++) {
            f32x4 kv = kr[c];
            acc += q[4 * c + 0] * kv[0] + q[4 * c + 1] * kv[1]
                 + q[4 * c + 2] * kv[2] + q[4 * c + 3] * kv[3];
        }
        s[j] = acc;
        mx = fmaxf(mx, acc);
    }
    float l = 0.f;
    #pragma unroll
    for (int j = 0; j < 49; j++) { float e = __expf(s[j] - mx); s[j] = e; l += e; }
    const float inv = 1.0f / l;

    float o[HD] = {};
    #pragma unroll
    for (int j = 0; j < 49; j++) {
        const float p = s[j];
        const f32x4* vr = (const f32x4*)vs[j];
        #pragma unroll
        for (int c = 0; c < 8; c++) {
            f32x4 vv = vr[c];
            o[4 * c + 0] += p * vv[0]; o[4 * c + 1] += p * vv[1];
            o[4 * c + 2] += p * vv[2]; o[4 * c + 3] += p * vv[3];
        }
    }

    unsigned short* op = out + (size_t)tok * DIM + h * 32;
    #pragma unroll
    for (int c = 0; c < 8; c++) {
        u16x4 u;
        u[0] = f2bf(o[4 * c + 0] * inv); u[1] = f2bf(o[4 * c + 1] * inv);
        u[2] = f2bf(o[4 * c + 2] * inv); u[3] = f2bf(o[4 * c + 3] * inv);
        *(u16x4*)(op + 4 * c) = u;
    }
}

extern "C" void kernel_launch(void* const* d_in, const int* in_sizes, int n_in,
                              void* d_out, int out_size, void* d_ws, size_t ws_size,
                              hipStream_t stream) {
    const float* x      = (const float*)d_in[0];
    const float* qkv_w  = (const float*)d_in[1];
    const float* qkv_b  = (const float*)d_in[2];
    const float* proj_w = (const float*)d_in[3];
    const float* proj_b = (const float*)d_in[4];
    float* out = (float*)d_out;

    char* ws = (char*)d_ws;
    unsigned short* qkv_bf = (unsigned short*)ws;
    unsigned short* xa_bf  = (unsigned short*)(ws + (size_t)MTOK * 1152 * 2);
    unsigned short* qw_bf  = (unsigned short*)(ws + (size_t)MTOK * 1152 * 2 + (size_t)MTOK * DIM * 2);
    unsigned short* pw_bf  = qw_bf + 3 * DIM * DIM;

    const int n4 = MTOK * DIM / 4;
    cvt_x_kernel<<<(n4 + 255) / 256, 256, 0, stream>>>(x, xa_bf, n4);
    cvt_w_kernel<<<(4 * DIM * DIM + 255) / 256, 256, 0, stream>>>(qkv_w, proj_w, qw_bf, pw_bf);

    // QKV: grid (784 m-tiles) x (9 n-tiles)
    gemm_bt<true><<<(MTOK / 128) * 9, 256, 0, stream>>>(xa_bf, qw_bf, qkv_b, qkv_bf, 3 * DIM, 9);

    attn_win<<<2048 * NH, 64, 0, stream>>>(qkv_bf, xa_bf);

    // proj: grid (784 m-tiles) x (3 n-tiles)
    gemm_bt<false><<<(MTOK / 128) * 3, 256, 0, stream>>>(xa_bf, pw_bf, proj_b, out, DIM, 3);
}